// Round 5
// baseline (145.631 us; speedup 1.0000x reference)
//
#include <hip/hip_runtime.h>

// Fused SSIM loss. B=32, C=1, 512x512, 11x11 separable Gaussian.
// Tile 64x32, raw (p,t) interleaved float2 in LDS, per-thread horizontal
// blur + register vertical scatter (8-row strip), SSIM inline.
// This round: force VOP3P packed fp32 math (v_pk_fma_f32 / v_pk_mul_f32)
// via inline asm — guarantees 2-wide packing AND pins accumulators into
// VGPR pairs (no AGPR round-trips).
typedef float v2f __attribute__((ext_vector_type(2)));

#define PK_FMA(acc, a, b) \
    asm("v_pk_fma_f32 %0, %1, %2, %0" : "+v"(acc) : "v"(a), "v"(b))
#define PK_MUL(d, a, b) \
    asm("v_pk_mul_f32 %0, %1, %2" : "=v"(d) : "v"(a), "v"(b))

#define B_    32
#define H_    512
#define W_    512
#define TW    64
#define TH    32
#define SR    8              // output rows per thread strip
#define SCAN  (SR + 10)      // 18 h-rows per strip
#define RROWS (TH + 10)      // 42 raw rows staged
#define LDW   76             // LDS row stride (float2 elements)
#define NBLK  (B_ * (W_/TW) * (H_/TH))   // 32*8*16 = 4096

__global__ __launch_bounds__(256, 5)
void ssim_main(const float* __restrict__ pred,
               const float* __restrict__ targ,
               const float* __restrict__ win,
               float* __restrict__ partial)
{
    __shared__ v2f   spt[RROWS][LDW];   // (p,t) pairs, 25.5 KiB
    __shared__ float wg[12];
    __shared__ float wsum[4];

    const int tid = threadIdx.x;
    const int bid = blockIdx.x;
    const int b   = bid >> 7;        // 8x16 = 128 tiles per image
    const int rem = bid & 127;
    const int ty  = rem >> 3;        // 0..15
    const int tx  = rem & 7;         // 0..7
    const int x0  = tx * TW - 5;
    const int y0  = ty * TH - 5;

    // 1-D gaussian = row sums of the 2-D window (window sums to 1).
    if (tid < 11) {
        float s = 0.f;
        #pragma unroll
        for (int j = 0; j < 11; ++j) s += win[tid * 11 + j];
        wg[tid] = s;
    }

    const float* pb = pred + (size_t)b * (H_ * W_);
    const float* tb = targ + (size_t)b * (H_ * W_);

    // ---- Stage interleaved raw tile, zero-padded (SAME conv). ----
    const bool interior = (tx > 0) & (tx < 7) & (ty > 0) & (ty < 15);
    if (interior) {
        for (int i = tid; i < RROWS * LDW; i += 256) {
            const int ly = i / LDW;
            const int lc = i - ly * LDW;
            const size_t off = (size_t)(y0 + ly) * W_ + (x0 + lc);
            v2f v;
            v.x = pb[off];
            v.y = tb[off];
            spt[ly][lc] = v;
        }
    } else {
        for (int i = tid; i < RROWS * LDW; i += 256) {
            const int ly = i / LDW;
            const int lc = i - ly * LDW;
            const int gy = y0 + ly, gx = x0 + lc;
            v2f v = {0.f, 0.f};
            if ((unsigned)gy < (unsigned)H_ && (unsigned)gx < (unsigned)W_) {
                const size_t off = (size_t)gy * W_ + gx;
                v.x = pb[off];
                v.y = tb[off];
            }
            spt[ly][lc] = v;
        }
    }
    __syncthreads();

    // Broadcast weight pairs (hoisted so taps pay zero broadcast cost).
    v2f w2[11];
    #pragma unroll
    for (int k = 0; k < 11; ++k) {
        const float wv = wg[k];
        w2[k].x = wv;
        w2[k].y = wv;
    }

    const int lx    = tid & 63;          // output column
    const int rbase = (tid >> 6) * SR;   // first raw row of strip

    v2f   A01[SR], A23[SR];   // (mu_p, mu_t), (E p^2, E t^2) pending rows
    float A4[SR];             // E p*t
    #pragma unroll
    for (int o = 0; o < SR; ++o) {
        A01[o] = (v2f){0.f, 0.f};
        A23[o] = (v2f){0.f, 0.f};
        A4[o]  = 0.f;
    }

    float lsum = 0.f;

    #pragma unroll
    for (int j = 0; j < SCAN; ++j) {
        const v2f* row = &spt[rbase + j][lx];
        // Horizontal 11-tap blur of (p,t), (p^2,t^2), p*t — packed fp32.
        v2f h01 = {0.f, 0.f}, h23 = {0.f, 0.f};
        float h4 = 0.f;
        #pragma unroll
        for (int k = 0; k < 11; ++k) {
            const v2f pt = row[k];
            v2f sq;
            PK_MUL(sq, pt, pt);
            PK_FMA(h01, w2[k], pt);
            PK_FMA(h23, w2[k], sq);
            h4 = fmaf(w2[k].x, pt.x * pt.y, h4);
        }
        // Vertical scatter: output row o uses h-rows o..o+10 (static folds).
        #pragma unroll
        for (int o = 0; o < SR; ++o) {
            if (o <= j && (j - o) < 11) {
                PK_FMA(A01[o], w2[j - o], h01);
                PK_FMA(A23[o], w2[j - o], h23);
                A4[o] = fmaf(w2[j - o].x, h4, A4[o]);
            }
        }
        // Output row j-10 complete: SSIM, accumulate.
        if (j >= 10) {
            const int o = j - 10;
            const float mp = A01[o].x, mt = A01[o].y;
            const float mp2 = mp * mp, mt2 = mt * mt, mpt = mp * mt;
            const float vp = fmaxf(A23[o].x - mp2, 0.f);
            const float vt = fmaxf(A23[o].y - mt2, 0.f);
            const float cv = A4[o] - mpt;
            const float num = (2.f * mpt + 1e-4f) * (2.f * cv + 9e-4f);
            const float den = (mp2 + mt2 + 1e-4f) * (vp + vt + 9e-4f);
            lsum += num * __builtin_amdgcn_rcpf(den + 1e-8f);
        }
    }

    // ---- Block reduce -> one float partial per block. ----
    #pragma unroll
    for (int off = 32; off > 0; off >>= 1)
        lsum += __shfl_down(lsum, off, 64);
    const int wid = tid >> 6, lane = tid & 63;
    if (lane == 0) wsum[wid] = lsum;
    __syncthreads();
    if (tid == 0)
        partial[bid] = wsum[0] + wsum[1] + wsum[2] + wsum[3];
}

__global__ __launch_bounds__(256)
void ssim_reduce(const float* __restrict__ partial, float* __restrict__ out)
{
    __shared__ double ws[4];
    double s = 0.0;
    for (int i = threadIdx.x; i < NBLK; i += 256) s += (double)partial[i];
    #pragma unroll
    for (int off = 32; off > 0; off >>= 1)
        s += __shfl_down(s, off, 64);
    if ((threadIdx.x & 63) == 0) ws[threadIdx.x >> 6] = s;
    __syncthreads();
    if (threadIdx.x == 0) {
        const double tot = ws[0] + ws[1] + ws[2] + ws[3];
        const double n = (double)B_ * (double)H_ * (double)W_;
        out[0] = (float)(1.0 - tot / n);
    }
}

extern "C" void kernel_launch(void* const* d_in, const int* in_sizes, int n_in,
                              void* d_out, int out_size, void* d_ws, size_t ws_size,
                              hipStream_t stream)
{
    const float* pred = (const float*)d_in[0];
    const float* targ = (const float*)d_in[1];
    const float* win  = (const float*)d_in[2];
    float* out     = (float*)d_out;
    float* partial = (float*)d_ws;      // NBLK floats = 16 KiB scratch

    ssim_main<<<NBLK, 256, 0, stream>>>(pred, targ, win, partial);
    ssim_reduce<<<1, 256, 0, stream>>>(partial, out);
}

// Round 6
// 125.299 us; speedup vs baseline: 1.1623x; 1.1623x over previous
//
#include <hip/hip_runtime.h>

// Fused SSIM loss via MFMA separable blur. B=32, C=1, 512x512, 11x11 gaussian.
// Blur = two banded matmuls with constant band matrix A[m][k] = g[k-m] (bf16):
//   pass1 (vertical):  V[yo][x] = sum_k g[k-yo] * raw[k][x]     (raw^T in LDS)
//   pass2 (horizontal) Out^T[xo][yo] = sum_k g[k-xo] * V[yo][X0+k]
// 4 planes: p, t, s=p^2+t^2, q=p*t (blur linearity folds the 5th).
// MFMA fp32 accumulate; bf16 staging error ~1e-3 << 2e-2 threshold.
typedef short  s16x8 __attribute__((ext_vector_type(8)));
typedef unsigned short u16x8 __attribute__((ext_vector_type(8)));
typedef float  f32x4 __attribute__((ext_vector_type(4)));

#define B_   32
#define H_   512
#define W_   512
#define TX_  64              // output tile width
#define TY_  32              // output tile height
#define RX_  80              // raw^T x-rows staged (74 used, pad to chunk*16)
#define RYP_ 48              // raw^T y-stride (42 used; mult of 8 for b128)
#define VXP_ 88              // v row stride (80 used; mult of 8, conflict pad)
#define NBLK (B_ * (W_/TX_) * (H_/TY_))   // 32*8*16 = 4096

__device__ __forceinline__ unsigned short f2bf(float x) {
    unsigned u = __builtin_bit_cast(unsigned, x);
    u += 0x7FFFu + ((u >> 16) & 1u);          // RTNE
    return (unsigned short)(u >> 16);
}

__global__ __launch_bounds__(256, 3)
void ssim_main(const float* __restrict__ pred,
               const float* __restrict__ targ,
               const float* __restrict__ win,
               float* __restrict__ partial)
{
    __shared__ __align__(16) unsigned short rawT[4][RX_][RYP_]; // [plane][x][y] 30.0 KiB
    __shared__ __align__(16) unsigned short vbuf[4][TY_][VXP_]; // [plane][y][x] 22.0 KiB
    __shared__ float gw[16];
    __shared__ float wsum[4];

    const int tid  = threadIdx.x;
    const int lane = tid & 63;
    const int wv   = tid >> 6;
    const int bid  = blockIdx.x;
    const int b    = bid >> 7;          // 8 x-panels * 16 y-panels = 128/image
    const int rem  = bid & 127;
    const int ty   = rem >> 3;          // 0..15
    const int tx   = rem & 7;           // 0..7
    const int x0g  = tx * TX_ - 5;
    const int y0g  = ty * TY_ - 5;

    // 1-D gaussian = row sums of the 2-D window (window sums to 1).
    if (tid < 11) {
        float s = 0.f;
        #pragma unroll
        for (int j = 0; j < 11; ++j) s += win[tid*11 + j];
        gw[tid] = s;
    }

    const float* pb = pred + (size_t)b * (H_*W_);
    const float* tb = targ + (size_t)b * (H_*W_);

    // ---- Stage raw^T planes (bf16), zero outside image (SAME pad). ----
    // 80 x-cols x 24 y-pairs; x fastest for coalesced global reads;
    // y-pairs pack two bf16 into one dword LDS write.
    for (int idx = tid; idx < RX_ * 24; idx += 256) {
        const int x_l = idx % RX_;
        const int rp  = idx / RX_;
        const int gx  = x0g + x_l;
        const int gy0 = y0g + 2*rp;
        const bool xv = (unsigned)gx < (unsigned)W_;
        float p0=0.f, t0=0.f, p1=0.f, t1=0.f;
        if (xv && (unsigned)gy0 < (unsigned)H_) {
            const size_t o = (size_t)gy0 * W_ + gx; p0 = pb[o]; t0 = tb[o];
        }
        if (xv && (unsigned)(gy0+1) < (unsigned)H_) {
            const size_t o = (size_t)(gy0+1) * W_ + gx; p1 = pb[o]; t1 = tb[o];
        }
        const float s0 = fmaf(p0,p0, t0*t0), s1 = fmaf(p1,p1, t1*t1);
        const float q0 = p0*t0,              q1 = p1*t1;
        const int yo = 2*rp;
        *(unsigned*)&rawT[0][x_l][yo] = (unsigned)f2bf(p0) | ((unsigned)f2bf(p1) << 16);
        *(unsigned*)&rawT[1][x_l][yo] = (unsigned)f2bf(t0) | ((unsigned)f2bf(t1) << 16);
        *(unsigned*)&rawT[2][x_l][yo] = (unsigned)f2bf(s0) | ((unsigned)f2bf(s1) << 16);
        *(unsigned*)&rawT[3][x_l][yo] = (unsigned)f2bf(q0) | ((unsigned)f2bf(q1) << 16);
    }
    __syncthreads();

    // ---- Constant band fragment A[m][k] = g[k-m] (m=lane&15, k=quad*8+j). ----
    const int mrow = lane & 15;
    const int quad = lane >> 4;
    s16x8 afr;
    #pragma unroll
    for (int j = 0; j < 8; ++j) {
        const int d = quad*8 + j - mrow;
        const float f = (d >= 0 && d < 11) ? gw[d] : 0.f;
        afr[j] = (short)f2bf(f);
    }
    const f32x4 zero4 = {0.f, 0.f, 0.f, 0.f};

    // ---- Pass 1: vertical blur. wave wv handles plane wv. ----
    // V[Yt+m][X0c+n] = sum_k A[m][k] * rawT[plane][X0c+n][Yt+k]
    #pragma unroll
    for (int it = 0; it < 10; ++it) {           // 5 x-chunks x 2 y-tiles
        const int X0c = (it >> 1) * 16;
        const int Yt  = (it & 1) * 16;
        const int xcol = X0c + mrow;            // n
        const u16x8 braw = *(const u16x8*)&rawT[wv][xcol][Yt + quad*8];
        const s16x8 bfr  = __builtin_bit_cast(s16x8, braw);
        const f32x4 d = __builtin_amdgcn_mfma_f32_16x16x32_bf16(afr, bfr, zero4, 0, 0, 0);
        #pragma unroll
        for (int r = 0; r < 4; ++r)             // row = quad*4+r
            vbuf[wv][Yt + quad*4 + r][xcol] = f2bf(d[r]);
    }
    __syncthreads();

    // ---- Pass 2: horizontal blur + SSIM. wave wv handles x-tile X0=16*wv. ----
    float lsum = 0.f;
    const int X0 = wv * 16;
    #pragma unroll
    for (int yt = 0; yt < 2; ++yt) {
        const int Y0c = yt * 16;
        f32x4 dq[4];
        #pragma unroll
        for (int pl = 0; pl < 4; ++pl) {
            const u16x8 bv = *(const u16x8*)&vbuf[pl][Y0c + mrow][X0 + quad*8];
            const s16x8 bfr = __builtin_bit_cast(s16x8, bv);
            dq[pl] = __builtin_amdgcn_mfma_f32_16x16x32_bf16(afr, bfr, zero4, 0, 0, 0);
        }
        // D[m=xo][n=yo]: lane holds out^T at col yo=mrow, rows xo=quad*4+r.
        #pragma unroll
        for (int r = 0; r < 4; ++r) {
            const float mp = dq[0][r], mt = dq[1][r];
            const float sv = dq[2][r], qv = dq[3][r];
            const float mp2 = mp*mp, mt2 = mt*mt, mpt = mp*mt;
            const float sig = fmaxf(sv - mp2 - mt2, 0.f);   // vp+vt
            const float cv  = qv - mpt;
            const float num = (2.f*mpt + 1e-4f) * (2.f*cv + 9e-4f);
            const float den = (mp2 + mt2 + 1e-4f) * (sig + 9e-4f);
            lsum += num * __builtin_amdgcn_rcpf(den + 1e-8f);
        }
    }

    // ---- Block reduce -> one float partial per block. ----
    #pragma unroll
    for (int off = 32; off > 0; off >>= 1)
        lsum += __shfl_down(lsum, off, 64);
    if (lane == 0) wsum[wv] = lsum;
    __syncthreads();
    if (tid == 0)
        partial[bid] = wsum[0] + wsum[1] + wsum[2] + wsum[3];
}

__global__ __launch_bounds__(256)
void ssim_reduce(const float* __restrict__ partial, float* __restrict__ out)
{
    __shared__ double ws[4];
    double s = 0.0;
    for (int i = threadIdx.x; i < NBLK; i += 256) s += (double)partial[i];
    #pragma unroll
    for (int off = 32; off > 0; off >>= 1)
        s += __shfl_down(s, off, 64);
    if ((threadIdx.x & 63) == 0) ws[threadIdx.x >> 6] = s;
    __syncthreads();
    if (threadIdx.x == 0) {
        const double tot = ws[0] + ws[1] + ws[2] + ws[3];
        const double n = (double)B_ * (double)H_ * (double)W_;
        out[0] = (float)(1.0 - tot / n);
    }
}

extern "C" void kernel_launch(void* const* d_in, const int* in_sizes, int n_in,
                              void* d_out, int out_size, void* d_ws, size_t ws_size,
                              hipStream_t stream)
{
    const float* pred = (const float*)d_in[0];
    const float* targ = (const float*)d_in[1];
    const float* win  = (const float*)d_in[2];
    float* out     = (float*)d_out;
    float* partial = (float*)d_ws;      // NBLK floats = 16 KiB scratch

    ssim_main<<<NBLK, 256, 0, stream>>>(pred, targ, win, partial);
    ssim_reduce<<<1, 256, 0, stream>>>(partial, out);
}